// Round 3
// baseline (301.494 us; speedup 1.0000x reference)
//
#include <hip/hip_runtime.h>
#include <hip/hip_bf16.h>

// IO-HMM fwd/bwd chain + projection for MI355X (gfx950).
// L=256 steps, B=128 batch, S=256 states, NL=64 labels.
//
// Kernel 1 (chain): R15 = R12 geometry (16 waves x 1 M-tile, the best of
//   the three measured: 16x1=215us, 8x2=225us, 4x4=250us -- step time
//   ~2000cyc is INVARIANT to wave geometry, so not LDS-throughput bound;
//   attacking the serial critical path instead):
//   (a) em prefetch ring depth 3 (loop unrolled x3, static slots; 255=3*85
//       no tail): emb gather is a 32MB-table random access, ~200-900cyc
//       latency; at depth 1 part of it sat on the critical path each step.
//   (b) MFMA accumulation split 8-deep -> 2x4-deep + f32x4 add: halves
//       exposed dependent-MFMA latency.
//   (c) fw/g global store moved AFTER the barrier (reg-only by then).
//   Carry layout / RNE packs / f16 single-product T / odd stride 67 /
//   lds-only barrier unchanged. REVERT precision to 2-product if
//   absmax > 396.8.
// Kernel 2 (score): R11 version unchanged (gap is timed-region overhead).

typedef _Float16 half8 __attribute__((ext_vector_type(8)));
typedef _Float16 half4 __attribute__((ext_vector_type(4)));
typedef float    f32x4 __attribute__((ext_vector_type(4)));
typedef unsigned long long u64;

#define LL 256
#define BB 128
#define SS 256
#define BT 16
#define RSTR8 67   // carry/p-plane row stride in 8B units (ODD -> conflict-free)
#define RSTRO 65   // o-plane row stride in 8B units (ODD -> conflict-free)

static __device__ __forceinline__ f32x4 mfma16f(half8 a, half8 b, f32x4 c) {
  return __builtin_amdgcn_mfma_f32_16x16x32_f16(a, b, c, 0, 0, 0);
}

// LDS-only barrier: order ds ops, leave vmcnt (global loads/stores) in flight.
static __device__ __forceinline__ void lds_barrier() {
  __asm__ __volatile__("s_waitcnt lgkmcnt(0)\n\ts_barrier" ::: "memory");
}

// Round-to-nearest-even f16 pack (NOT cvt_pkrtz -- RTZ bias compounds over
// the 255-step chain into ~6% coherent shrink; R8 erratum).
static __device__ __forceinline__ u64 pack4(f32x4 v) {
  union { half4 h; u64 u; } x;
  x.h[0] = (_Float16)v[0];
  x.h[1] = (_Float16)v[1];
  x.h[2] = (_Float16)v[2];
  x.h[3] = (_Float16)v[3];
  return x.u;
}

// 16B logical fragment as two b64 reads (8B-aligned odd-stride layout).
static __device__ __forceinline__ half8 read_frag_s(const u64* plane, int row,
                                                    int kt, int q, int stride8) {
  const int o = row * stride8 + kt * 8 + q * 2;
  union { u64 u[2]; half8 v; } x;
  x.u[0] = plane[o];
  x.u[1] = plane[o + 1];
  return x.v;
}

__global__ __launch_bounds__(1024, 4)
void hmm_chain(const int* __restrict__ sent, const float* __restrict__ emb,
               const float* __restrict__ T, _Float16* __restrict__ fwh,
               _Float16* __restrict__ gh)
{
  __shared__ u64 s_carry[2][BT * RSTR8]; // [buf][row*stride], single f16 plane
  __shared__ int s_tok[BT * 257];        // [batch][l], stride 257

  const int tid  = threadIdx.x;
  const int lane = tid & 63;
  const int w    = tid >> 6;   // wave 0..15 -> states [16w, 16w+16)
  const int m    = lane & 15;  // A row-in-tile / B col (= batch)
  const int q    = lane >> 4;  // quad

  const int  bid = blockIdx.x;
  const bool fwd = (bid < 8);
  const int  bg0 = (fwd ? bid : bid - 8) * BT;
  _Float16* const obuf = fwd ? fwh : gh;
  const int  st  = 16 * w + 4 * q;       // this lane's first state

  // ---- stage sentence tokens ----
  for (int idx = tid; idx < BT * LL; idx += 1024) {
    int bb = idx >> 8, l2 = idx & 255;
    s_tok[bb * 257 + l2] = sent[(bg0 + bb) * LL + l2];
  }
  __syncthreads();

  // ---- load T fragments (A operand), single f16: 8 frags = 32 regs
  half8 a_hi[8];
#pragma unroll
  for (int kt = 0; kt < 8; ++kt) {
    const int r0 = 16 * w + m;           // state (M index)
    const int kb = 32 * kt + 8 * q;      // k base
    float v[8];
    if (fwd) {
      f32x4 f0 = *(const f32x4*)(T + r0 * 256 + kb);
      f32x4 f1 = *(const f32x4*)(T + r0 * 256 + kb + 4);
#pragma unroll
      for (int j = 0; j < 4; ++j) { v[j] = f0[j]; v[4 + j] = f1[j]; }
    } else {
#pragma unroll
      for (int j = 0; j < 8; ++j) v[j] = T[(kb + j) * 256 + r0]; // T^T
    }
    half8 hi;
#pragma unroll
    for (int j = 0; j < 8; ++j) hi[j] = (_Float16)v[j];   // RNE
    a_hi[kt] = hi;
  }

  // ---- init carry at l0 + first-row store ----
  const int l0 = fwd ? 0 : (LL - 1);
  {
    const int tok0 = s_tok[m * 257 + l0];
    f32x4 e0 = *(const f32x4*)(emb + (size_t)tok0 * 256 + st);
    u64 pc = pack4(e0);                       // carry = em[l0] both dirs
    f32x4 one = 1.0f;
    u64 po = fwd ? pc : pack4(one);           // g[L-1] = 1
    *(u64*)(obuf + (size_t)(l0 * BB + bg0 + m) * SS + st) = po;
    s_carry[0][m * RSTR8 + 4 * w + q] = pc;
  }

  // em gather for step su (clamped), direction-mapped
  auto ldem = [&](int su) -> f32x4 {
    su = su < LL ? su : LL - 1;
    const int ln = fwd ? su : (LL - 1) - su;
    const int tk = s_tok[m * 257 + ln];
    return *(const f32x4*)(emb + (size_t)tk * 256 + st);
  };

  // ---- prefetch em for steps 1..3 (ring depth 3, static slots) ----
  f32x4 emr0 = ldem(1);
  f32x4 emr1 = ldem(2);
  f32x4 emr2 = ldem(3);
  __syncthreads();

  // one chain step: consume emr (em for step ss), refill it with em(ss+3)
  auto step = [&](int ss, f32x4& emr) {
    const int l  = fwd ? ss : (LL - 1) - ss;
    const int rb = (ss - 1) & 1, wb = ss & 1;

    const u64* pr = &s_carry[rb][0];
    half8 bfr[8];
#pragma unroll
    for (int kt = 0; kt < 8; ++kt)
      bfr[kt] = read_frag_s(pr, m, kt, q, RSTR8);

    f32x4 em_now = emr;
    emr = ldem(ss + 3);                  // deep prefetch (3 steps ahead)

    // 2x4-deep independent MFMA chains (halved dependent latency) + add
    f32x4 aA = 0.0f, aB = 0.0f;
#pragma unroll
    for (int kt = 0; kt < 4; ++kt) aA = mfma16f(a_hi[kt], bfr[kt], aA);
#pragma unroll
    for (int kt = 4; kt < 8; ++kt) aB = mfma16f(a_hi[kt], bfr[kt], aB);
    f32x4 v  = aA + aB;                  // pre-em matmul result
    f32x4 cn = v * em_now;               // new carry

    u64 p0 = pack4(cn);
    s_carry[wb][m * RSTR8 + 4 * w + q] = p0;
    u64 sv = fwd ? p0 : pack4(v);        // fwd stores fw[l]; bwd stores g[l]=v
    lds_barrier();  // LDS ordering only; globals stay in flight
    // global store post-barrier: off the serial path, reg-only inputs
    *(u64*)(obuf + (size_t)(l * BB + bg0 + m) * SS + st) = sv;
  };

  // ---- main chain: 255 steps = 85 x 3 (static ring slots, no tail) ----
  for (int s = 1; s < LL; s += 3) {
    step(s + 0, emr0);
    step(s + 1, emr1);
    step(s + 2, emr2);
  }
}

__global__ __launch_bounds__(256, 2)
void hmm_score(const _Float16* __restrict__ fwh, const _Float16* __restrict__ gh,
               const float* __restrict__ outm, float* __restrict__ score)
{
  __shared__ u64 p_pl[64 * RSTR8];   // p = fw*g, [row][k] f16
  __shared__ u64 o_pl[64 * RSTRO];   // outm^T,   [n][k]  f16

  const int tid  = threadIdx.x;
  const int lane = tid & 63;
  const int w    = tid >> 6;
  const int rh   = w >> 1;     // row half: rows [32rh, 32rh+32)
  const int np   = w & 1;      // n-pair: n-tiles {2np, 2np+1}
  const int m    = lane & 15;
  const int q    = lane >> 4;
  const int R0   = blockIdx.x * 64;  // row = l*128 + b

  // ---- stage outm -> o_pl[n][k] f16 (RNE, hi only), coalesced f32x4 loads
  {
    _Float16* o_h = (_Float16*)o_pl;
    for (int i = tid; i < 4096; i += 256) {
      f32x4 v = *(const f32x4*)(outm + i * 4);   // flat = k*64+n
      int k = i >> 4, n0 = (i & 15) * 4;
#pragma unroll
      for (int r = 0; r < 4; ++r)
        o_h[(n0 + r) * (RSTRO * 4) + k] = (_Float16)v[r];
    }
  }

  // ---- stage p = fw * g (f16 packed mul, RNE) ----
  for (int idx = tid; idx < 64 * 64; idx += 256) {
    int row = idx >> 6, c = idx & 63;       // c = 8B column index
    union { u64 u; half4 h; } a, b, p;
    a.u = *(const u64*)(fwh + (size_t)(R0 + row) * 256 + c * 4);
    b.u = *(const u64*)(gh  + (size_t)(R0 + row) * 256 + c * 4);
    p.h = a.h * b.h;                        // v_pk_mul_f16 x2
    p_pl[row * RSTR8 + c] = p.u;
  }
  lds_barrier();

  f32x4 acc[2][2];
#pragma unroll
  for (int j = 0; j < 2; ++j)
#pragma unroll
    for (int jn = 0; jn < 2; ++jn) acc[j][jn] = 0.0f;

#pragma unroll
  for (int kt = 0; kt < 8; ++kt) {
    half8 of[2];
#pragma unroll
    for (int jn = 0; jn < 2; ++jn)
      of[jn] = read_frag_s(o_pl, 16 * (2 * np + jn) + m, kt, q, RSTRO);
#pragma unroll
    for (int j = 0; j < 2; ++j) {
      half8 pf = read_frag_s(p_pl, 32 * rh + 16 * j + m, kt, q, RSTR8);
#pragma unroll
      for (int jn = 0; jn < 2; ++jn)
        acc[j][jn] = mfma16f(pf, of[jn], acc[j][jn]);
    }
  }

#pragma unroll
  for (int j = 0; j < 2; ++j) {
#pragma unroll
    for (int jn = 0; jn < 2; ++jn) {
#pragma unroll
      for (int r = 0; r < 4; ++r) {
        int row = R0 + 32 * rh + 16 * j + 4 * q + r;
        int l = row >> 7, b = row & 127;
        score[(size_t)b * 16384 + l * 64 + 16 * (2 * np + jn) + m] = acc[j][jn][r];
      }
    }
  }
}

extern "C" void kernel_launch(void* const* d_in, const int* in_sizes, int n_in,
                              void* d_out, int out_size, void* d_ws, size_t ws_size,
                              hipStream_t stream) {
  (void)in_sizes; (void)n_in; (void)out_size; (void)ws_size;
  const int*   sent = (const int*)d_in[0];
  const float* emb  = (const float*)d_in[1];
  const float* T    = (const float*)d_in[2];
  const float* outm = (const float*)d_in[3];
  _Float16* fwh = (_Float16*)d_ws;                  // [L][B][S] f16, 16 MB
  _Float16* gh  = fwh + (size_t)LL * BB * SS;       // [L][B][S] f16, 16 MB

  hmm_chain<<<16, 1024, 0, stream>>>(sent, emb, T, fwh, gh);
  hmm_score<<<512, 256, 0, stream>>>(fwh, gh, outm, (float*)d_out);
}